// Round 2
// baseline (496.308 us; speedup 1.0000x reference)
//
#include <hip/hip_runtime.h>
#include <hip/hip_fp16.h>

#define HH 512
#define WW 512
#define NB 8
#define TS 16
#define LROW 19
#define LPLANE (18*LROW)
// pbuf row = 64 f16 channels = 128 B, XOR-swizzled in 16B chunks by ((row>>1)&7)
#define SW(row) (((row) >> 1) & 7)

typedef unsigned int u32;
typedef __attribute__((ext_vector_type(4))) _Float16 f16x4;
typedef __attribute__((ext_vector_type(8))) _Float16 f16x8;
typedef __attribute__((ext_vector_type(4))) float f32x4;

// ---------------- threefry2x32 core ----------------
__device__ __forceinline__ u32 rotl32(u32 v, int n){ return (v<<n)|(v>>(32-n)); }
struct U2 { u32 x, y; };

__device__ __forceinline__ U2 threefry2x32(u32 k0, u32 k1, u32 x0, u32 x1){
  u32 k2 = k0 ^ k1 ^ 0x1BD11BDAu;
  x0 += k0; x1 += k1;
  const int RA[4] = {13,15,26,6};
  const int RB[4] = {17,29,16,24};
  #pragma unroll
  for(int i=0;i<4;i++){ x0+=x1; x1=rotl32(x1,RA[i]); x1^=x0; }
  x0 += k1; x1 += k2 + 1u;
  #pragma unroll
  for(int i=0;i<4;i++){ x0+=x1; x1=rotl32(x1,RB[i]); x1^=x0; }
  x0 += k2; x1 += k0 + 2u;
  #pragma unroll
  for(int i=0;i<4;i++){ x0+=x1; x1=rotl32(x1,RA[i]); x1^=x0; }
  x0 += k0; x1 += k1 + 3u;
  #pragma unroll
  for(int i=0;i<4;i++){ x0+=x1; x1=rotl32(x1,RB[i]); x1^=x0; }
  x0 += k1; x1 += k2 + 4u;
  #pragma unroll
  for(int i=0;i<4;i++){ x0+=x1; x1=rotl32(x1,RA[i]); x1^=x0; }
  x0 += k2; x1 += k0 + 5u;
  U2 r; r.x = x0; r.y = x1; return r;
}

// partitionable draw (modern JAX default): counter=(0,i), out = x^y
__device__ __forceinline__ u32 pbits(u32 k0, u32 k1, u32 i){
  U2 o = threefry2x32(k0, k1, 0u, i);
  return o.x ^ o.y;
}

__device__ __forceinline__ float xla_erfinv(float x){
  float w = -log1pf(-x*x);
  float p;
  if (w < 5.0f){
    w -= 2.5f;
    p = 2.81022636e-08f;
    p = fmaf(p,w, 3.43273939e-07f);
    p = fmaf(p,w,-3.5233877e-06f);
    p = fmaf(p,w,-4.39150654e-06f);
    p = fmaf(p,w, 0.00021858087f);
    p = fmaf(p,w,-0.00125372503f);
    p = fmaf(p,w,-0.00417768164f);
    p = fmaf(p,w, 0.246640727f);
    p = fmaf(p,w, 1.50140941f);
  } else {
    w = sqrtf(w) - 3.0f;
    p = -0.000200214257f;
    p = fmaf(p,w, 0.000100950558f);
    p = fmaf(p,w, 0.00134934322f);
    p = fmaf(p,w,-0.00367342844f);
    p = fmaf(p,w, 0.00573950773f);
    p = fmaf(p,w,-0.0076224613f);
    p = fmaf(p,w, 0.00943887047f);
    p = fmaf(p,w, 1.00167406f);
    p = fmaf(p,w, 2.83297682f);
  }
  return p*x;
}

__device__ __forceinline__ float normal_from_bits(u32 bits){
  const float LO = -0.99999994f;
  u32 fb = (bits >> 9) | 0x3F800000u;
  float f = __uint_as_float(fb) - 1.0f;
  float u = f * 2.0f + LO;
  u = fmaxf(LO, u);
  return 1.41421356f * xla_erfinv(u);
}

__device__ __forceinline__ u32 h2_as_u32(__half2 h){ return *(u32*)&h; }
__device__ __forceinline__ __half2 u32_as_h2(u32 v){ return *(__half2*)&v; }

// ---------------- prep: weights -> B-fragment order (f16) + noise keys ----------------
// B-frag 16x16x32: lane L: n=(L&15), k=(L>>4)*8+j
// f 0..7: layer1 (f=kh*4+nc); f 8..11: layer2 (f=8+kh*2+nc); f 12: heads N=16
__global__ void prep_w(const float* __restrict__ w1, const float* __restrict__ w2,
                       const float* __restrict__ wrgb, const float* __restrict__ wvel,
                       const float* __restrict__ whid,
                       const float* __restrict__ brgb, const float* __restrict__ bvel,
                       const float* __restrict__ bhid,
                       const int* __restrict__ seedp,
                       unsigned short* __restrict__ wfrag, float* __restrict__ bcat,
                       u32* __restrict__ nkeys){
  int tid = threadIdx.x;
  for (int f = tid >> 6; f < 13; f += 4){
    int lane = tid & 63, quad = lane >> 4, m = lane & 15;
    #pragma unroll
    for (int j = 0; j < 8; ++j){
      float val;
      if (f < 8){
        int kh = f >> 2, nc = f & 3;
        int k = kh*32 + quad*8 + j, n = nc*16 + m;
        val = w1[k*64 + n];
      } else if (f < 12){
        int g = f - 8, kh = g >> 1, nc = g & 1;
        int k = kh*32 + quad*8 + j, n = nc*16 + m;
        val = w2[k*32 + n];
      } else {
        int k = quad*8 + j;
        val = (m < 3) ? wrgb[k*3 + m]
            : (m == 4 || m == 5) ? wvel[k*2 + (m-4)]
            : (m >= 8) ? whid[k*8 + (m-8)] : 0.0f;
      }
      wfrag[(f*64 + lane)*8 + j] = __half_as_ushort(__float2half(val));
    }
  }
  if (tid < 16)
    bcat[tid] = (tid < 3) ? brgb[tid]
              : (tid == 4 || tid == 5) ? bvel[tid-4]
              : (tid >= 8) ? bhid[tid-8] : 0.0f;
  if (tid == 0){
    // foldlike split (partitionable) — uniform, hoisted out of nca_main
    u32 K1 = (u32)seedp[0];
    U2 nk = threefry2x32(0u, K1, 0u, 1u);
    U2 c1 = threefry2x32(nk.x, nk.y, 0u, 0u);
    U2 c2 = threefry2x32(nk.x, nk.y, 0u, 1u);
    nkeys[0] = c1.x; nkeys[1] = c1.y; nkeys[2] = c2.x; nkeys[3] = c2.y;
  }
}

// ---------------- kernel A: f16 stencil + f16 MFMA MLP + exact-f32 epilogue ----------------
// LDS = 32768 B exactly -> 5 blocks/CU (vs 4 at 34816). __launch_bounds__(256,5)
// caps VGPRs ~100; per-gi fused compute+store keeps peak live regs ~85.
__global__ __launch_bounds__(256, 5) void nca_main(
    const float* __restrict__ st, const int* __restrict__ seedp,
    const float* __restrict__ b1, const float* __restrict__ b2,
    const unsigned short* __restrict__ wfrag, const float* __restrict__ bcat,
    const u32* __restrict__ nkeys,
    float* __restrict__ out, u32* __restrict__ vxy, float* __restrict__ m0p)
{
  // union: stage planes (8 x LPLANE u32 = 10944 B), then pbuf (256 rows x 128 B
  // = 32768 B, chunk-swizzled), then dsb (256 x 17 f32 = 17408 B)
  __shared__ __align__(16) unsigned char smem[32768];
  u32 (*ls2)[LPLANE] = (u32 (*)[LPLANE])smem;

  const int tid  = threadIdx.x;
  const int lane = tid & 63, wv = tid >> 6;
  const int quad = lane >> 4, mm = lane & 15;
  const int bx = blockIdx.x, by = blockIdx.y, b = blockIdx.z;
  const int x0t = bx*TS, y0t = by*TS;
  const float* __restrict__ sb = st + (size_t)b*HH*WW*16;

  // layer-1 B fragments + biases + rng keys (L2-hot, uniform-ish)
  f16x8 BfA[8];
  #pragma unroll
  for (int f = 0; f < 8; ++f)
    BfA[f] = *(const f16x8*)(wfrag + (f*64 + lane)*8);
  float bias1[4], bias2[2];
  #pragma unroll
  for (int nc = 0; nc < 4; ++nc) bias1[nc] = b1[nc*16 + mm];
  #pragma unroll
  for (int nc = 0; nc < 2; ++nc) bias2[nc] = b2[nc*16 + mm];
  float biasH = bcat[mm];
  const int seed = seedp[0];
  const u32 k1a = nkeys[0], k1b = nkeys[1], k2a = nkeys[2], k2b = nkeys[3];

  // stage 18x18 px x 8 half2-pairs
  for (int t = tid; t < 18*18*4; t += 256){
    int pix = t >> 2, part = t & 3;
    int py = pix / 18, px = pix - py*18;
    int gy = (y0t + py - 1) & (HH-1);
    int gx = (x0t + px - 1) & (WW-1);
    const float4 v = *(const float4*)(sb + ((gy*WW + gx)*16 + part*4));
    int li = py*LROW + px;
    ls2[part*2  ][li] = h2_as_u32(__floats2half2_rn(v.x, v.y));
    ls2[part*2+1][li] = h2_as_u32(__floats2half2_rn(v.z, v.w));
  }
  __syncthreads();

  const int lx = tid & 15, ly = tid >> 4;
  const int ctr = (ly+1)*LROW + (lx+1);

  // ---- perception in packed f16; results held in 32 u32 regs (constant-indexed) ----
  const __half2 two    = __float2half2_rn(2.0f);
  const __half2 eighth = __float2half2_rn(0.125f);
  const __half2 quart  = __float2half2_rn(0.25f);
  const __half2 neg4   = __float2half2_rn(-4.0f);
  u32 rid[8], rgx[8], rgy[8], rlp[8];
  #pragma unroll
  for (int cp = 0; cp < 8; ++cp){
    const u32* pl = ls2[cp];
    __half2 t00 = u32_as_h2(pl[ctr-LROW-1]), t01 = u32_as_h2(pl[ctr-LROW]), t02 = u32_as_h2(pl[ctr-LROW+1]);
    __half2 t10 = u32_as_h2(pl[ctr-1]),      t11 = u32_as_h2(pl[ctr]),      t12 = u32_as_h2(pl[ctr+1]);
    __half2 t20 = u32_as_h2(pl[ctr+LROW-1]), t21 = u32_as_h2(pl[ctr+LROW]), t22 = u32_as_h2(pl[ctr+LROW+1]);
    __half2 sR = __hfma2(two, t12, __hadd2(t02, t22));
    __half2 sL = __hfma2(two, t10, __hadd2(t00, t20));
    __half2 sB = __hfma2(two, t21, __hadd2(t20, t22));
    __half2 sT = __hfma2(two, t01, __hadd2(t00, t02));
    __half2 sC = __hadd2(__hadd2(t10, t12), __hadd2(t01, t21));
    rid[cp] = h2_as_u32(t11);
    rgx[cp] = h2_as_u32(__hmul2(__hsub2(sR, sL), eighth));
    rgy[cp] = h2_as_u32(__hmul2(__hsub2(sB, sT), eighth));
    rlp[cp] = h2_as_u32(__hmul2(__hfma2(neg4, t11, sC), quart));
  }
  __syncthreads();   // all stencil reads done; smem becomes pbuf

  // ---- pack to pbuf, swizzled: dword j of row t lands at j ^ (SW(t)<<2) ----
  {
    u32* pb32 = (u32*)smem;
    const int rsw = SW(tid) << 2;
    #pragma unroll
    for (int cp = 0; cp < 8; ++cp){
      pb32[tid*32 + (( 0 + cp) ^ rsw)] = rid[cp];   // ch 0..15
      pb32[tid*32 + (( 8 + cp) ^ rsw)] = rgx[cp];   // ch 16..31
      pb32[tid*32 + ((16 + cp) ^ rsw)] = rgy[cp];   // ch 32..47
      pb32[tid*32 + ((24 + cp) ^ rsw)] = rlp[cp];   // ch 48..63
    }
  }
  // from here on, all LDS traffic is intra-wave (wave wv owns pixels 64wv..64wv+63)

  const int rowbase = wv*4;
  const _Float16* pb16 = (const _Float16*)smem;
  unsigned short* pbuf = (unsigned short*)smem;

  // fragment read: 16B chunk c of row px, swizzled -> single ds_read_b128
  auto loadfrag = [&](int px, int chunk) -> f16x8 {
    return *(const f16x8*)(pb16 + px*64 + ((chunk ^ SW(px)) * 8));
  };

  // ---- layer 1 (per-gi fused compute+store: reads of gi's rows precede writes) ----
  #pragma unroll
  for (int gi = 0; gi < 4; ++gi){
    int px = (rowbase+gi)*16 + mm;
    f16x8 a0 = loadfrag(px, quad);
    f16x8 a1 = loadfrag(px, 4 + quad);
    f32x4 C[4];
    #pragma unroll
    for (int nc = 0; nc < 4; ++nc){
      f32x4 c; c[0]=bias1[nc]; c[1]=bias1[nc]; c[2]=bias1[nc]; c[3]=bias1[nc];
      c = __builtin_amdgcn_mfma_f32_16x16x32_f16(a0, BfA[nc],   c, 0,0,0);
      c = __builtin_amdgcn_mfma_f32_16x16x32_f16(a1, BfA[4+nc], c, 0,0,0);
      C[nc] = c;
    }
    #pragma unroll
    for (int nc = 0; nc < 4; ++nc)
      #pragma unroll
      for (int r = 0; r < 4; ++r){
        int row = (rowbase+gi)*16 + quad*4 + r;
        pbuf[row*64 + ((nc*16 + mm) ^ (SW(row) << 3))] =
            __half_as_ushort(__float2half(fmaxf(C[nc][r], 0.0f)));
      }
  }

  // issue layer-2/heads B fragments + own-pixel exact-f32 state early:
  // latency hides under layer-2/heads MFMA work
  f16x8 BfB[5];
  #pragma unroll
  for (int f = 0; f < 5; ++f)
    BfB[f] = *(const f16x8*)(wfrag + ((8+f)*64 + lane)*8);
  const int ygl = y0t + ly, xgl = x0t + lx;
  const float* scp = sb + ((size_t)(ygl*WW + xgl))*16;
  float4 s0 = *(const float4*)(scp+0),  s1 = *(const float4*)(scp+4);
  float4 s2 = *(const float4*)(scp+8),  s3 = *(const float4*)(scp+12);

  // ---- layer 2 ----
  #pragma unroll
  for (int gi = 0; gi < 4; ++gi){
    int px = (rowbase+gi)*16 + mm;
    f16x8 a0 = loadfrag(px, quad);
    f16x8 a1 = loadfrag(px, 4 + quad);
    f32x4 C[2];
    #pragma unroll
    for (int nc = 0; nc < 2; ++nc){
      f32x4 c; c[0]=bias2[nc]; c[1]=bias2[nc]; c[2]=bias2[nc]; c[3]=bias2[nc];
      c = __builtin_amdgcn_mfma_f32_16x16x32_f16(a0, BfB[nc],   c, 0,0,0);
      c = __builtin_amdgcn_mfma_f32_16x16x32_f16(a1, BfB[2+nc], c, 0,0,0);
      C[nc] = c;
    }
    #pragma unroll
    for (int nc = 0; nc < 2; ++nc)
      #pragma unroll
      for (int r = 0; r < 4; ++r){
        int row = (rowbase+gi)*16 + quad*4 + r;
        pbuf[row*64 + ((nc*16 + mm) ^ (SW(row) << 3))] =
            __half_as_ushort(__float2half(fmaxf(C[nc][r], 0.0f)));
      }
  }

  // ---- heads (K=32, a0 only) ----
  f32x4 C3[4];
  #pragma unroll
  for (int gi = 0; gi < 4; ++gi){
    int px = (rowbase+gi)*16 + mm;
    f16x8 a0 = loadfrag(px, quad);
    f32x4 c; c[0]=biasH; c[1]=biasH; c[2]=biasH; c[3]=biasH;
    C3[gi] = __builtin_amdgcn_mfma_f32_16x16x32_f16(a0, BfB[4], c, 0,0,0);
  }
  __syncthreads();   // dsb rows overlap other waves' pbuf rows
  {
    float* dsb = (float*)smem;   // 256 x 17 f32
    #pragma unroll
    for (int gi = 0; gi < 4; ++gi)
      #pragma unroll
      for (int r = 0; r < 4; ++r)
        dsb[((rowbase+gi)*16 + quad*4 + r)*17 + mm] = C3[gi][r];
  }

  // ---- epilogue: exact f32 (sc preloaded, L2-hot) ----
  const float* dsb = (const float*)smem;
  u32 K0 = 0u, K1 = (u32)seed;
  const u32 pix = ((u32)b*HH + ygl)*WW + xgl;
  u32 mbits = pbits(K0, K1, pix);
  float m = ((int)mbits >= 0) ? 1.0f : 0.0f;

  float sc[16] = {s0.x,s0.y,s0.z,s0.w, s1.x,s1.y,s1.z,s1.w,
                  s2.x,s2.y,s2.z,s2.w, s3.x,s3.y,s3.z,s3.w};
  float ds[16], ns[16];
  #pragma unroll
  for (int ch = 0; ch < 16; ++ch) ds[ch] = dsb[tid*17 + ch];
  ds[3] = 0.0f; ds[6] = 0.0f; ds[7] = 0.0f;   // zero heads (cols were zero anyway)
  #pragma unroll
  for (int ch = 0; ch < 16; ++ch) ns[ch] = sc[ch] + ds[ch]*m;

  ns[4] = 0.95f * fminf(fmaxf(ns[4], -1.0f), 1.0f);
  ns[5] = 0.95f * fminf(fmaxf(ns[5], -1.0f), 1.0f);
  ns[0] = fminf(fmaxf(ns[0], 0.0f), 1.0f);
  ns[1] = fminf(fmaxf(ns[1], 0.0f), 1.0f);
  ns[2] = fminf(fmaxf(ns[2], 0.0f), 1.0f);
  ns[3] = sc[3];

  float* __restrict__ op = out + (size_t)pix*16;
  *(float4*)(op+ 0) = make_float4(ns[0],ns[1],ns[2],ns[3]);
  *(float4*)(op+ 4) = make_float4(ns[4],ns[5],ns[6],ns[7]);
  *(float4*)(op+ 8) = make_float4(ns[8],ns[9],ns[10],ns[11]);
  *(float4*)(op+12) = make_float4(ns[12],ns[13],ns[14],ns[15]);

  float vx = ns[4] + 0.2f*normal_from_bits(pbits(k1a,k1b,pix));
  float vy = ns[5] + 0.2f*normal_from_bits(pbits(k2a,k2b,pix));
  vxy[pix] = h2_as_u32(__floats2half2_rn(vx, vy));
  m0p[pix] = sc[3];
}

// ---------------- fused advect x2 + diffuse (halo-3 tile) ----------------
// |v| <= 0.95 + 0.2*5.6sigma ~ 2.07 -> per-step displacement <= 0.52 px < 1.
#define AT 32
__global__ __launch_bounds__(256) void advect_fused(
    const float* __restrict__ m0, const u32* __restrict__ vxy,
    float* __restrict__ out)
{
  __shared__ float sm0[38][39];
  __shared__ u32   sv [36][37];
  __shared__ float sm1[36][37];
  __shared__ float sm2[34][35];
  const int tid = threadIdx.x;
  const int X0 = blockIdx.x*AT, Y0 = blockIdx.y*AT, b = blockIdx.z;
  const size_t base = ((size_t)b) << 18;

  for (int t = tid; t < 38*38; t += 256){
    int ly = t/38, lx = t - ly*38;
    int gy = (Y0-3+ly)&511, gx = (X0-3+lx)&511;
    sm0[ly][lx] = m0[base + (gy<<9) + gx];
  }
  for (int t = tid; t < 36*36; t += 256){
    int ly = t/36, lx = t - ly*36;
    int gy = (Y0-2+ly)&511, gx = (X0-2+lx)&511;
    sv[ly][lx] = vxy[base + (gy<<9) + gx];
  }
  __syncthreads();

  // step 1: m1 on 36x36 (globals Y0-2..Y0+33)
  for (int t = tid; t < 36*36; t += 256){
    int ly = t/36, lx = t - ly*36;
    int gy = (Y0-2+ly)&511, gx = (X0-2+lx)&511;
    __half2 hv = u32_as_h2(sv[ly][lx]);
    float vx = __low2float(hv), vyv = __high2float(hv);
    float sy = (float)gy - vyv*0.25f;
    float sx = (float)gx - vx *0.25f;
    float y0f = floorf(sy), x0f = floorf(sx);
    float fy = sy - y0f, fx = sx - x0f;
    int l0y = (((int)y0f) - Y0 + 3) & 511;
    int l0x = (((int)x0f) - X0 + 3) & 511;
    float m00 = sm0[l0y][l0x],   m01 = sm0[l0y][l0x+1];
    float m10 = sm0[l0y+1][l0x], m11 = sm0[l0y+1][l0x+1];
    sm1[ly][lx] = (1.0f-fy)*((1.0f-fx)*m00 + fx*m01) + fy*((1.0f-fx)*m10 + fx*m11);
  }
  __syncthreads();

  // step 2: m2 on 34x34 (globals Y0-1..Y0+32); v local = +1
  for (int t = tid; t < 34*34; t += 256){
    int ly = t/34, lx = t - ly*34;
    int gy = (Y0-1+ly)&511, gx = (X0-1+lx)&511;
    __half2 hv = u32_as_h2(sv[ly+1][lx+1]);
    float vx = __low2float(hv), vyv = __high2float(hv);
    float sy = (float)gy - vyv*0.25f;
    float sx = (float)gx - vx *0.25f;
    float y0f = floorf(sy), x0f = floorf(sx);
    float fy = sy - y0f, fx = sx - x0f;
    int l0y = (((int)y0f) - Y0 + 2) & 511;
    int l0x = (((int)x0f) - X0 + 2) & 511;
    float m00 = sm1[l0y][l0x],   m01 = sm1[l0y][l0x+1];
    float m10 = sm1[l0y+1][l0x], m11 = sm1[l0y+1][l0x+1];
    sm2[ly][lx] = (1.0f-fy)*((1.0f-fx)*m00 + fx*m01) + fy*((1.0f-fx)*m10 + fx*m11);
  }
  __syncthreads();

  // diffuse 32x32 -> out ch3
  for (int t = tid; t < 32*32; t += 256){
    int ly = t >> 5, lx = t & 31;
    int gy = Y0 + ly, gx = X0 + lx;
    float c = sm2[ly+1][lx+1];
    float r = sm2[ly+1][lx+2], l = sm2[ly+1][lx];
    float d = sm2[ly+2][lx+1], u = sm2[ly][lx+1];
    out[(base + (gy<<9) + gx)*16 + 3] = c + 0.05f*((r+l+d+u)*0.25f - c);
  }
}

// ---------------- launch ----------------
extern "C" void kernel_launch(void* const* d_in, const int* in_sizes, int n_in,
                              void* d_out, int out_size, void* d_ws, size_t ws_size,
                              hipStream_t stream)
{
  const float* st   = (const float*)d_in[0];
  const int*   seed = (const int*)  d_in[1];
  const float* w1   = (const float*)d_in[2];
  const float* b1   = (const float*)d_in[3];
  const float* w2   = (const float*)d_in[4];
  const float* b2   = (const float*)d_in[5];
  const float* wrgb = (const float*)d_in[6];
  const float* brgb = (const float*)d_in[7];
  const float* wvel = (const float*)d_in[8];
  const float* bvel = (const float*)d_in[9];
  const float* whid = (const float*)d_in[10];
  const float* bhid = (const float*)d_in[11];
  float* out = (float*)d_out;

  const int npix = NB*HH*WW;                 // 2^21
  float* m0p = (float*)d_ws;                 // 8 MB
  u32*   vxy = (u32*)(m0p + npix);           // 8 MB
  unsigned short* wfrag = (unsigned short*)(vxy + npix);  // 13312 B
  float* bcat = (float*)(wfrag + 13*64*8);   // 64 B
  u32* nkeys = (u32*)(bcat + 16);            // 16 B

  prep_w<<<1, 256, 0, stream>>>(w1, w2, wrgb, wvel, whid, brgb, bvel, bhid, seed,
                                wfrag, bcat, nkeys);

  dim3 gridA(WW/TS, HH/TS, NB);
  nca_main<<<gridA, 256, 0, stream>>>(st, seed, b1, b2, wfrag, bcat, nkeys, out, vxy, m0p);

  dim3 gridB(WW/AT, HH/AT, NB);
  advect_fused<<<gridB, 256, 0, stream>>>(m0p, vxy, out);
}

// Round 3
// 368.722 us; speedup vs baseline: 1.3460x; 1.3460x over previous
//
#include <hip/hip_runtime.h>
#include <hip/hip_fp16.h>

#define HH 512
#define WW 512
#define NB 8
#define TS 16
#define LROW 19
#define LPLANE (18*LROW)
// pbuf row = 64 f16 channels = 128 B, XOR-swizzled in 16B chunks by ((row>>1)&7)
#define SW(row) (((row) >> 1) & 7)

typedef unsigned int u32;
typedef __attribute__((ext_vector_type(4))) _Float16 f16x4;
typedef __attribute__((ext_vector_type(8))) _Float16 f16x8;
typedef __attribute__((ext_vector_type(4))) float f32x4;

// ---------------- threefry2x32 core ----------------
__device__ __forceinline__ u32 rotl32(u32 v, int n){ return (v<<n)|(v>>(32-n)); }
struct U2 { u32 x, y; };

__device__ __forceinline__ U2 threefry2x32(u32 k0, u32 k1, u32 x0, u32 x1){
  u32 k2 = k0 ^ k1 ^ 0x1BD11BDAu;
  x0 += k0; x1 += k1;
  const int RA[4] = {13,15,26,6};
  const int RB[4] = {17,29,16,24};
  #pragma unroll
  for(int i=0;i<4;i++){ x0+=x1; x1=rotl32(x1,RA[i]); x1^=x0; }
  x0 += k1; x1 += k2 + 1u;
  #pragma unroll
  for(int i=0;i<4;i++){ x0+=x1; x1=rotl32(x1,RB[i]); x1^=x0; }
  x0 += k2; x1 += k0 + 2u;
  #pragma unroll
  for(int i=0;i<4;i++){ x0+=x1; x1=rotl32(x1,RA[i]); x1^=x0; }
  x0 += k0; x1 += k1 + 3u;
  #pragma unroll
  for(int i=0;i<4;i++){ x0+=x1; x1=rotl32(x1,RB[i]); x1^=x0; }
  x0 += k1; x1 += k2 + 4u;
  #pragma unroll
  for(int i=0;i<4;i++){ x0+=x1; x1=rotl32(x1,RA[i]); x1^=x0; }
  x0 += k2; x1 += k0 + 5u;
  U2 r; r.x = x0; r.y = x1; return r;
}

// partitionable draw (modern JAX default): counter=(0,i), out = x^y
__device__ __forceinline__ u32 pbits(u32 k0, u32 k1, u32 i){
  U2 o = threefry2x32(k0, k1, 0u, i);
  return o.x ^ o.y;
}

__device__ __forceinline__ float xla_erfinv(float x){
  float w = -log1pf(-x*x);
  float p;
  if (w < 5.0f){
    w -= 2.5f;
    p = 2.81022636e-08f;
    p = fmaf(p,w, 3.43273939e-07f);
    p = fmaf(p,w,-3.5233877e-06f);
    p = fmaf(p,w,-4.39150654e-06f);
    p = fmaf(p,w, 0.00021858087f);
    p = fmaf(p,w,-0.00125372503f);
    p = fmaf(p,w,-0.00417768164f);
    p = fmaf(p,w, 0.246640727f);
    p = fmaf(p,w, 1.50140941f);
  } else {
    w = sqrtf(w) - 3.0f;
    p = -0.000200214257f;
    p = fmaf(p,w, 0.000100950558f);
    p = fmaf(p,w, 0.00134934322f);
    p = fmaf(p,w,-0.00367342844f);
    p = fmaf(p,w, 0.00573950773f);
    p = fmaf(p,w,-0.0076224613f);
    p = fmaf(p,w, 0.00943887047f);
    p = fmaf(p,w, 1.00167406f);
    p = fmaf(p,w, 2.83297682f);
  }
  return p*x;
}

__device__ __forceinline__ float normal_from_bits(u32 bits){
  const float LO = -0.99999994f;
  u32 fb = (bits >> 9) | 0x3F800000u;
  float f = __uint_as_float(fb) - 1.0f;
  float u = f * 2.0f + LO;
  u = fmaxf(LO, u);
  return 1.41421356f * xla_erfinv(u);
}

__device__ __forceinline__ u32 h2_as_u32(__half2 h){ return *(u32*)&h; }
__device__ __forceinline__ __half2 u32_as_h2(u32 v){ return *(__half2*)&v; }

// ---------------- prep: weights -> B-fragment order (f16) + noise keys ----------------
// B-frag 16x16x32: lane L: n=(L&15), k=(L>>4)*8+j
// f 0..7: layer1 (f=kh*4+nc); f 8..11: layer2 (f=8+kh*2+nc); f 12: heads N=16
__global__ void prep_w(const float* __restrict__ w1, const float* __restrict__ w2,
                       const float* __restrict__ wrgb, const float* __restrict__ wvel,
                       const float* __restrict__ whid,
                       const float* __restrict__ brgb, const float* __restrict__ bvel,
                       const float* __restrict__ bhid,
                       const int* __restrict__ seedp,
                       unsigned short* __restrict__ wfrag, float* __restrict__ bcat,
                       u32* __restrict__ nkeys){
  int tid = threadIdx.x;
  for (int f = tid >> 6; f < 13; f += 4){
    int lane = tid & 63, quad = lane >> 4, m = lane & 15;
    #pragma unroll
    for (int j = 0; j < 8; ++j){
      float val;
      if (f < 8){
        int kh = f >> 2, nc = f & 3;
        int k = kh*32 + quad*8 + j, n = nc*16 + m;
        val = w1[k*64 + n];
      } else if (f < 12){
        int g = f - 8, kh = g >> 1, nc = g & 1;
        int k = kh*32 + quad*8 + j, n = nc*16 + m;
        val = w2[k*32 + n];
      } else {
        int k = quad*8 + j;
        val = (m < 3) ? wrgb[k*3 + m]
            : (m == 4 || m == 5) ? wvel[k*2 + (m-4)]
            : (m >= 8) ? whid[k*8 + (m-8)] : 0.0f;
      }
      wfrag[(f*64 + lane)*8 + j] = __half_as_ushort(__float2half(val));
    }
  }
  if (tid < 16)
    bcat[tid] = (tid < 3) ? brgb[tid]
              : (tid == 4 || tid == 5) ? bvel[tid-4]
              : (tid >= 8) ? bhid[tid-8] : 0.0f;
  if (tid == 0){
    // foldlike split (partitionable) — uniform, hoisted out of nca_main
    u32 K1 = (u32)seedp[0];
    U2 nk = threefry2x32(0u, K1, 0u, 1u);
    U2 c1 = threefry2x32(nk.x, nk.y, 0u, 0u);
    U2 c2 = threefry2x32(nk.x, nk.y, 0u, 1u);
    nkeys[0] = c1.x; nkeys[1] = c1.y; nkeys[2] = c2.x; nkeys[3] = c2.y;
  }
}

// ---------------- kernel A: f16 stencil + f16 MFMA MLP + exact-f32 epilogue ----------------
// LDS = 32768 B. __launch_bounds__(256,4): unified VGPR+AGPR cap 128 — spill-free
// (round-2's (256,5) capped the UNIFIED file at ~102 -> 48 VGPR -> 370 MB scratch).
__global__ __launch_bounds__(256, 4) void nca_main(
    const float* __restrict__ st, const int* __restrict__ seedp,
    const float* __restrict__ b1, const float* __restrict__ b2,
    const unsigned short* __restrict__ wfrag, const float* __restrict__ bcat,
    const u32* __restrict__ nkeys,
    float* __restrict__ out, u32* __restrict__ vxy, float* __restrict__ m0p)
{
  // union: stage planes (8 x LPLANE u32 = 10944 B), then pbuf (256 rows x 128 B
  // = 32768 B, chunk-swizzled), then dsb (256 x 17 f32 = 17408 B)
  __shared__ __align__(16) unsigned char smem[32768];
  u32 (*ls2)[LPLANE] = (u32 (*)[LPLANE])smem;

  const int tid  = threadIdx.x;
  const int lane = tid & 63, wv = tid >> 6;
  const int quad = lane >> 4, mm = lane & 15;
  const int bx = blockIdx.x, by = blockIdx.y, b = blockIdx.z;
  const int x0t = bx*TS, y0t = by*TS;
  const float* __restrict__ sb = st + (size_t)b*HH*WW*16;

  const int seed = seedp[0];
  const u32 k1a = nkeys[0], k1b = nkeys[1], k2a = nkeys[2], k2b = nkeys[3];

  // stage 18x18 px x 8 half2-pairs
  for (int t = tid; t < 18*18*4; t += 256){
    int pix = t >> 2, part = t & 3;
    int py = pix / 18, px = pix - py*18;
    int gy = (y0t + py - 1) & (HH-1);
    int gx = (x0t + px - 1) & (WW-1);
    const float4 v = *(const float4*)(sb + ((gy*WW + gx)*16 + part*4));
    int li = py*LROW + px;
    ls2[part*2  ][li] = h2_as_u32(__floats2half2_rn(v.x, v.y));
    ls2[part*2+1][li] = h2_as_u32(__floats2half2_rn(v.z, v.w));
  }
  __syncthreads();

  const int lx = tid & 15, ly = tid >> 4;
  const int ctr = (ly+1)*LROW + (lx+1);

  // ---- perception in packed f16; results held in 32 u32 regs (constant-indexed) ----
  const __half2 two    = __float2half2_rn(2.0f);
  const __half2 eighth = __float2half2_rn(0.125f);
  const __half2 quart  = __float2half2_rn(0.25f);
  const __half2 neg4   = __float2half2_rn(-4.0f);
  u32 rid[8], rgx[8], rgy[8], rlp[8];
  #pragma unroll
  for (int cp = 0; cp < 8; ++cp){
    const u32* pl = ls2[cp];
    __half2 t00 = u32_as_h2(pl[ctr-LROW-1]), t01 = u32_as_h2(pl[ctr-LROW]), t02 = u32_as_h2(pl[ctr-LROW+1]);
    __half2 t10 = u32_as_h2(pl[ctr-1]),      t11 = u32_as_h2(pl[ctr]),      t12 = u32_as_h2(pl[ctr+1]);
    __half2 t20 = u32_as_h2(pl[ctr+LROW-1]), t21 = u32_as_h2(pl[ctr+LROW]), t22 = u32_as_h2(pl[ctr+LROW+1]);
    __half2 sR = __hfma2(two, t12, __hadd2(t02, t22));
    __half2 sL = __hfma2(two, t10, __hadd2(t00, t20));
    __half2 sB = __hfma2(two, t21, __hadd2(t20, t22));
    __half2 sT = __hfma2(two, t01, __hadd2(t00, t02));
    __half2 sC = __hadd2(__hadd2(t10, t12), __hadd2(t01, t21));
    rid[cp] = h2_as_u32(t11);
    rgx[cp] = h2_as_u32(__hmul2(__hsub2(sR, sL), eighth));
    rgy[cp] = h2_as_u32(__hmul2(__hsub2(sB, sT), eighth));
    rlp[cp] = h2_as_u32(__hmul2(__hfma2(neg4, t11, sC), quart));
  }
  __syncthreads();   // all stencil reads done; smem becomes pbuf

  // ---- pack to pbuf, swizzled: dword j of row t lands at j ^ (SW(t)<<2) ----
  {
    u32* pb32 = (u32*)smem;
    const int rsw = SW(tid) << 2;
    #pragma unroll
    for (int cp = 0; cp < 8; ++cp){
      pb32[tid*32 + (( 0 + cp) ^ rsw)] = rid[cp];   // ch 0..15
      pb32[tid*32 + (( 8 + cp) ^ rsw)] = rgx[cp];   // ch 16..31
      pb32[tid*32 + ((16 + cp) ^ rsw)] = rgy[cp];   // ch 32..47
      pb32[tid*32 + ((24 + cp) ^ rsw)] = rlp[cp];   // ch 48..63
    }
  }
  // from here on, all LDS traffic is intra-wave (wave wv owns pixels 64wv..64wv+63)

  // ---- B fragments + biases loaded AFTER the pack: the 32 stencil regs and
  // the 32 fragment regs never overlap -> peak pressure stays well under 128.
  f16x8 BfA[8];
  #pragma unroll
  for (int f = 0; f < 8; ++f)
    BfA[f] = *(const f16x8*)(wfrag + (f*64 + lane)*8);
  float bias1[4], bias2[2];
  #pragma unroll
  for (int nc = 0; nc < 4; ++nc) bias1[nc] = b1[nc*16 + mm];
  #pragma unroll
  for (int nc = 0; nc < 2; ++nc) bias2[nc] = b2[nc*16 + mm];
  float biasH = bcat[mm];

  const int rowbase = wv*4;
  const _Float16* pb16 = (const _Float16*)smem;
  unsigned short* pbuf = (unsigned short*)smem;

  // fragment read: 16B chunk c of row px, swizzled -> single ds_read_b128
  auto loadfrag = [&](int px, int chunk) -> f16x8 {
    return *(const f16x8*)(pb16 + px*64 + ((chunk ^ SW(px)) * 8));
  };

  // ---- layer 1 (per-gi fused compute+store: reads of gi's rows precede writes) ----
  #pragma unroll
  for (int gi = 0; gi < 4; ++gi){
    int px = (rowbase+gi)*16 + mm;
    f16x8 a0 = loadfrag(px, quad);
    f16x8 a1 = loadfrag(px, 4 + quad);
    f32x4 C[4];
    #pragma unroll
    for (int nc = 0; nc < 4; ++nc){
      f32x4 c; c[0]=bias1[nc]; c[1]=bias1[nc]; c[2]=bias1[nc]; c[3]=bias1[nc];
      c = __builtin_amdgcn_mfma_f32_16x16x32_f16(a0, BfA[nc],   c, 0,0,0);
      c = __builtin_amdgcn_mfma_f32_16x16x32_f16(a1, BfA[4+nc], c, 0,0,0);
      C[nc] = c;
    }
    #pragma unroll
    for (int nc = 0; nc < 4; ++nc)
      #pragma unroll
      for (int r = 0; r < 4; ++r){
        int row = (rowbase+gi)*16 + quad*4 + r;
        pbuf[row*64 + ((nc*16 + mm) ^ (SW(row) << 3))] =
            __half_as_ushort(__float2half(fmaxf(C[nc][r], 0.0f)));
      }
  }

  // layer-2/heads B fragments: latency hides under layer-2 MFMA
  f16x8 BfB[5];
  #pragma unroll
  for (int f = 0; f < 5; ++f)
    BfB[f] = *(const f16x8*)(wfrag + ((8+f)*64 + lane)*8);

  // ---- layer 2 ----
  #pragma unroll
  for (int gi = 0; gi < 4; ++gi){
    int px = (rowbase+gi)*16 + mm;
    f16x8 a0 = loadfrag(px, quad);
    f16x8 a1 = loadfrag(px, 4 + quad);
    f32x4 C[2];
    #pragma unroll
    for (int nc = 0; nc < 2; ++nc){
      f32x4 c; c[0]=bias2[nc]; c[1]=bias2[nc]; c[2]=bias2[nc]; c[3]=bias2[nc];
      c = __builtin_amdgcn_mfma_f32_16x16x32_f16(a0, BfB[nc],   c, 0,0,0);
      c = __builtin_amdgcn_mfma_f32_16x16x32_f16(a1, BfB[2+nc], c, 0,0,0);
      C[nc] = c;
    }
    #pragma unroll
    for (int nc = 0; nc < 2; ++nc)
      #pragma unroll
      for (int r = 0; r < 4; ++r){
        int row = (rowbase+gi)*16 + quad*4 + r;
        pbuf[row*64 + ((nc*16 + mm) ^ (SW(row) << 3))] =
            __half_as_ushort(__float2half(fmaxf(C[nc][r], 0.0f)));
      }
  }

  // ---- heads (K=32, a0 only) ----
  f32x4 C3[4];
  #pragma unroll
  for (int gi = 0; gi < 4; ++gi){
    int px = (rowbase+gi)*16 + mm;
    f16x8 a0 = loadfrag(px, quad);
    f32x4 c; c[0]=biasH; c[1]=biasH; c[2]=biasH; c[3]=biasH;
    C3[gi] = __builtin_amdgcn_mfma_f32_16x16x32_f16(a0, BfB[4], c, 0,0,0);
  }

  // own-pixel exact-f32 state: issue now, latency hides under sync+dsb+threefry
  const int ygl = y0t + ly, xgl = x0t + lx;
  const float* scp = sb + ((size_t)(ygl*WW + xgl))*16;
  float4 s0 = *(const float4*)(scp+0),  s1 = *(const float4*)(scp+4);
  float4 s2 = *(const float4*)(scp+8),  s3 = *(const float4*)(scp+12);

  __syncthreads();   // dsb rows overlap other waves' pbuf rows
  {
    float* dsb = (float*)smem;   // 256 x 17 f32
    #pragma unroll
    for (int gi = 0; gi < 4; ++gi)
      #pragma unroll
      for (int r = 0; r < 4; ++r)
        dsb[((rowbase+gi)*16 + quad*4 + r)*17 + mm] = C3[gi][r];
  }

  // ---- epilogue: exact f32 ----
  const float* dsb = (const float*)smem;
  u32 K0 = 0u, K1 = (u32)seed;
  const u32 pix = ((u32)b*HH + ygl)*WW + xgl;
  u32 mbits = pbits(K0, K1, pix);
  float m = ((int)mbits >= 0) ? 1.0f : 0.0f;

  float sc[16] = {s0.x,s0.y,s0.z,s0.w, s1.x,s1.y,s1.z,s1.w,
                  s2.x,s2.y,s2.z,s2.w, s3.x,s3.y,s3.z,s3.w};
  float ds[16], ns[16];
  #pragma unroll
  for (int ch = 0; ch < 16; ++ch) ds[ch] = dsb[tid*17 + ch];
  ds[3] = 0.0f; ds[6] = 0.0f; ds[7] = 0.0f;   // zero heads (cols were zero anyway)
  #pragma unroll
  for (int ch = 0; ch < 16; ++ch) ns[ch] = sc[ch] + ds[ch]*m;

  ns[4] = 0.95f * fminf(fmaxf(ns[4], -1.0f), 1.0f);
  ns[5] = 0.95f * fminf(fmaxf(ns[5], -1.0f), 1.0f);
  ns[0] = fminf(fmaxf(ns[0], 0.0f), 1.0f);
  ns[1] = fminf(fmaxf(ns[1], 0.0f), 1.0f);
  ns[2] = fminf(fmaxf(ns[2], 0.0f), 1.0f);
  ns[3] = sc[3];

  float* __restrict__ op = out + (size_t)pix*16;
  *(float4*)(op+ 0) = make_float4(ns[0],ns[1],ns[2],ns[3]);
  *(float4*)(op+ 4) = make_float4(ns[4],ns[5],ns[6],ns[7]);
  *(float4*)(op+ 8) = make_float4(ns[8],ns[9],ns[10],ns[11]);
  *(float4*)(op+12) = make_float4(ns[12],ns[13],ns[14],ns[15]);

  float vx = ns[4] + 0.2f*normal_from_bits(pbits(k1a,k1b,pix));
  float vy = ns[5] + 0.2f*normal_from_bits(pbits(k2a,k2b,pix));
  vxy[pix] = h2_as_u32(__floats2half2_rn(vx, vy));
  m0p[pix] = sc[3];
}

// ---------------- fused advect x2 + diffuse (halo-3 tile) ----------------
// |v| <= 0.95 + 0.2*5.6sigma ~ 2.07 -> per-step displacement <= 0.52 px < 1.
#define AT 32
__global__ __launch_bounds__(256) void advect_fused(
    const float* __restrict__ m0, const u32* __restrict__ vxy,
    float* __restrict__ out)
{
  __shared__ float sm0[38][39];
  __shared__ u32   sv [36][37];
  __shared__ float sm1[36][37];
  __shared__ float sm2[34][35];
  const int tid = threadIdx.x;
  const int X0 = blockIdx.x*AT, Y0 = blockIdx.y*AT, b = blockIdx.z;
  const size_t base = ((size_t)b) << 18;

  for (int t = tid; t < 38*38; t += 256){
    int ly = t/38, lx = t - ly*38;
    int gy = (Y0-3+ly)&511, gx = (X0-3+lx)&511;
    sm0[ly][lx] = m0[base + (gy<<9) + gx];
  }
  for (int t = tid; t < 36*36; t += 256){
    int ly = t/36, lx = t - ly*36;
    int gy = (Y0-2+ly)&511, gx = (X0-2+lx)&511;
    sv[ly][lx] = vxy[base + (gy<<9) + gx];
  }
  __syncthreads();

  // step 1: m1 on 36x36 (globals Y0-2..Y0+33)
  for (int t = tid; t < 36*36; t += 256){
    int ly = t/36, lx = t - ly*36;
    int gy = (Y0-2+ly)&511, gx = (X0-2+lx)&511;
    __half2 hv = u32_as_h2(sv[ly][lx]);
    float vx = __low2float(hv), vyv = __high2float(hv);
    float sy = (float)gy - vyv*0.25f;
    float sx = (float)gx - vx *0.25f;
    float y0f = floorf(sy), x0f = floorf(sx);
    float fy = sy - y0f, fx = sx - x0f;
    int l0y = (((int)y0f) - Y0 + 3) & 511;
    int l0x = (((int)x0f) - X0 + 3) & 511;
    float m00 = sm0[l0y][l0x],   m01 = sm0[l0y][l0x+1];
    float m10 = sm0[l0y+1][l0x], m11 = sm0[l0y+1][l0x+1];
    sm1[ly][lx] = (1.0f-fy)*((1.0f-fx)*m00 + fx*m01) + fy*((1.0f-fx)*m10 + fx*m11);
  }
  __syncthreads();

  // step 2: m2 on 34x34 (globals Y0-1..Y0+32); v local = +1
  for (int t = tid; t < 34*34; t += 256){
    int ly = t/34, lx = t - ly*34;
    int gy = (Y0-1+ly)&511, gx = (X0-1+lx)&511;
    __half2 hv = u32_as_h2(sv[ly+1][lx+1]);
    float vx = __low2float(hv), vyv = __high2float(hv);
    float sy = (float)gy - vyv*0.25f;
    float sx = (float)gx - vx *0.25f;
    float y0f = floorf(sy), x0f = floorf(sx);
    float fy = sy - y0f, fx = sx - x0f;
    int l0y = (((int)y0f) - Y0 + 2) & 511;
    int l0x = (((int)x0f) - X0 + 2) & 511;
    float m00 = sm1[l0y][l0x],   m01 = sm1[l0y][l0x+1];
    float m10 = sm1[l0y+1][l0x], m11 = sm1[l0y+1][l0x+1];
    sm2[ly][lx] = (1.0f-fy)*((1.0f-fx)*m00 + fx*m01) + fy*((1.0f-fx)*m10 + fx*m11);
  }
  __syncthreads();

  // diffuse 32x32 -> out ch3
  for (int t = tid; t < 32*32; t += 256){
    int ly = t >> 5, lx = t & 31;
    int gy = Y0 + ly, gx = X0 + lx;
    float c = sm2[ly+1][lx+1];
    float r = sm2[ly+1][lx+2], l = sm2[ly+1][lx];
    float d = sm2[ly+2][lx+1], u = sm2[ly][lx+1];
    out[(base + (gy<<9) + gx)*16 + 3] = c + 0.05f*((r+l+d+u)*0.25f - c);
  }
}

// ---------------- launch ----------------
extern "C" void kernel_launch(void* const* d_in, const int* in_sizes, int n_in,
                              void* d_out, int out_size, void* d_ws, size_t ws_size,
                              hipStream_t stream)
{
  const float* st   = (const float*)d_in[0];
  const int*   seed = (const int*)  d_in[1];
  const float* w1   = (const float*)d_in[2];
  const float* b1   = (const float*)d_in[3];
  const float* w2   = (const float*)d_in[4];
  const float* b2   = (const float*)d_in[5];
  const float* wrgb = (const float*)d_in[6];
  const float* brgb = (const float*)d_in[7];
  const float* wvel = (const float*)d_in[8];
  const float* bvel = (const float*)d_in[9];
  const float* whid = (const float*)d_in[10];
  const float* bhid = (const float*)d_in[11];
  float* out = (float*)d_out;

  const int npix = NB*HH*WW;                 // 2^21
  float* m0p = (float*)d_ws;                 // 8 MB
  u32*   vxy = (u32*)(m0p + npix);           // 8 MB
  unsigned short* wfrag = (unsigned short*)(vxy + npix);  // 13312 B
  float* bcat = (float*)(wfrag + 13*64*8);   // 64 B
  u32* nkeys = (u32*)(bcat + 16);            // 16 B

  prep_w<<<1, 256, 0, stream>>>(w1, w2, wrgb, wvel, whid, brgb, bvel, bhid, seed,
                                wfrag, bcat, nkeys);

  dim3 gridA(WW/TS, HH/TS, NB);
  nca_main<<<gridA, 256, 0, stream>>>(st, seed, b1, b2, wfrag, bcat, nkeys, out, vxy, m0p);

  dim3 gridB(WW/AT, HH/AT, NB);
  advect_fused<<<gridB, 256, 0, stream>>>(m0p, vxy, out);
}

// Round 4
// 352.491 us; speedup vs baseline: 1.4080x; 1.0460x over previous
//
#include <hip/hip_runtime.h>
#include <hip/hip_fp16.h>

#define HH 512
#define WW 512
#define NB 8
#define TS 16
#define LROW 19
#define LPLANE (18*LROW)
// pbuf row = 64 f16 channels = 128 B, XOR-swizzled in 16B chunks by ((row>>1)&7)
#define SW(row) (((row) >> 1) & 7)

typedef unsigned int u32;
typedef __attribute__((ext_vector_type(4))) _Float16 f16x4;
typedef __attribute__((ext_vector_type(8))) _Float16 f16x8;
typedef __attribute__((ext_vector_type(4))) float f32x4;
typedef __attribute__((ext_vector_type(4))) u32 u32x4;

// ---------------- threefry2x32 core ----------------
__device__ __forceinline__ u32 rotl32(u32 v, int n){ return (v<<n)|(v>>(32-n)); }
struct U2 { u32 x, y; };

__device__ __forceinline__ U2 threefry2x32(u32 k0, u32 k1, u32 x0, u32 x1){
  u32 k2 = k0 ^ k1 ^ 0x1BD11BDAu;
  x0 += k0; x1 += k1;
  const int RA[4] = {13,15,26,6};
  const int RB[4] = {17,29,16,24};
  #pragma unroll
  for(int i=0;i<4;i++){ x0+=x1; x1=rotl32(x1,RA[i]); x1^=x0; }
  x0 += k1; x1 += k2 + 1u;
  #pragma unroll
  for(int i=0;i<4;i++){ x0+=x1; x1=rotl32(x1,RB[i]); x1^=x0; }
  x0 += k2; x1 += k0 + 2u;
  #pragma unroll
  for(int i=0;i<4;i++){ x0+=x1; x1=rotl32(x1,RA[i]); x1^=x0; }
  x0 += k0; x1 += k1 + 3u;
  #pragma unroll
  for(int i=0;i<4;i++){ x0+=x1; x1=rotl32(x1,RB[i]); x1^=x0; }
  x0 += k1; x1 += k2 + 4u;
  #pragma unroll
  for(int i=0;i<4;i++){ x0+=x1; x1=rotl32(x1,RA[i]); x1^=x0; }
  x0 += k2; x1 += k0 + 5u;
  U2 r; r.x = x0; r.y = x1; return r;
}

// partitionable draw (modern JAX default): counter=(0,i), out = x^y
__device__ __forceinline__ u32 pbits(u32 k0, u32 k1, u32 i){
  U2 o = threefry2x32(k0, k1, 0u, i);
  return o.x ^ o.y;
}

__device__ __forceinline__ float xla_erfinv(float x){
  // w = -log1p(-x*x); fmaf keeps the 1-x^2 cancellation exact to 1 ulp,
  // __logf (v_log_f32) replaces the log1pf lib expansion.
  float w = -__logf(fmaf(-x, x, 1.0f));
  float p;
  if (w < 5.0f){
    w -= 2.5f;
    p = 2.81022636e-08f;
    p = fmaf(p,w, 3.43273939e-07f);
    p = fmaf(p,w,-3.5233877e-06f);
    p = fmaf(p,w,-4.39150654e-06f);
    p = fmaf(p,w, 0.00021858087f);
    p = fmaf(p,w,-0.00125372503f);
    p = fmaf(p,w,-0.00417768164f);
    p = fmaf(p,w, 0.246640727f);
    p = fmaf(p,w, 1.50140941f);
  } else {
    w = sqrtf(w) - 3.0f;
    p = -0.000200214257f;
    p = fmaf(p,w, 0.000100950558f);
    p = fmaf(p,w, 0.00134934322f);
    p = fmaf(p,w,-0.00367342844f);
    p = fmaf(p,w, 0.00573950773f);
    p = fmaf(p,w,-0.0076224613f);
    p = fmaf(p,w, 0.00943887047f);
    p = fmaf(p,w, 1.00167406f);
    p = fmaf(p,w, 2.83297682f);
  }
  return p*x;
}

__device__ __forceinline__ float normal_from_bits(u32 bits){
  const float LO = -0.99999994f;
  u32 fb = (bits >> 9) | 0x3F800000u;
  float f = __uint_as_float(fb) - 1.0f;
  float u = f * 2.0f + LO;
  u = fmaxf(LO, u);
  return 1.41421356f * xla_erfinv(u);
}

__device__ __forceinline__ u32 h2_as_u32(__half2 h){ return *(u32*)&h; }
__device__ __forceinline__ __half2 u32_as_h2(u32 v){ return *(__half2*)&v; }

// ---------------- prep: weights -> B-fragment order (f16) + noise keys ----------------
// B-frag 16x16x32: lane L: n=(L&15), k=(L>>4)*8+j
// f 0..7: layer1 (f=kh*4+nc); f 8..11: layer2 (f=8+kh*2+nc); f 12: heads N=16
__global__ void prep_w(const float* __restrict__ w1, const float* __restrict__ w2,
                       const float* __restrict__ wrgb, const float* __restrict__ wvel,
                       const float* __restrict__ whid,
                       const float* __restrict__ brgb, const float* __restrict__ bvel,
                       const float* __restrict__ bhid,
                       const int* __restrict__ seedp,
                       unsigned short* __restrict__ wfrag, float* __restrict__ bcat,
                       u32* __restrict__ nkeys){
  int tid = threadIdx.x;
  for (int f = tid >> 6; f < 13; f += 4){
    int lane = tid & 63, quad = lane >> 4, m = lane & 15;
    #pragma unroll
    for (int j = 0; j < 8; ++j){
      float val;
      if (f < 8){
        int kh = f >> 2, nc = f & 3;
        int k = kh*32 + quad*8 + j, n = nc*16 + m;
        val = w1[k*64 + n];
      } else if (f < 12){
        int g = f - 8, kh = g >> 1, nc = g & 1;
        int k = kh*32 + quad*8 + j, n = nc*16 + m;
        val = w2[k*32 + n];
      } else {
        int k = quad*8 + j;
        val = (m < 3) ? wrgb[k*3 + m]
            : (m == 4 || m == 5) ? wvel[k*2 + (m-4)]
            : (m >= 8) ? whid[k*8 + (m-8)] : 0.0f;
      }
      wfrag[(f*64 + lane)*8 + j] = __half_as_ushort(__float2half(val));
    }
  }
  if (tid < 16)
    bcat[tid] = (tid < 3) ? brgb[tid]
              : (tid == 4 || tid == 5) ? bvel[tid-4]
              : (tid >= 8) ? bhid[tid-8] : 0.0f;
  if (tid == 0){
    // foldlike split (partitionable) — uniform, hoisted out of nca_main
    u32 K1 = (u32)seedp[0];
    U2 nk = threefry2x32(0u, K1, 0u, 1u);
    U2 c1 = threefry2x32(nk.x, nk.y, 0u, 0u);
    U2 c2 = threefry2x32(nk.x, nk.y, 0u, 1u);
    nkeys[0] = c1.x; nkeys[1] = c1.y; nkeys[2] = c2.x; nkeys[3] = c2.y;
  }
}

// ---------------- kernel A: f16 stencil + f16 MFMA MLP + exact-f32 epilogue ----------------
// LDS = 32768 B. __launch_bounds__(256,4): unified VGPR+AGPR cap 128 — spill-free
// (a (256,5) cap of ~96 caused 370 MB of scratch traffic in round 2).
__global__ __launch_bounds__(256, 4) void nca_main(
    const float* __restrict__ st, const int* __restrict__ seedp,
    const float* __restrict__ b1, const float* __restrict__ b2,
    const unsigned short* __restrict__ wfrag, const float* __restrict__ bcat,
    const u32* __restrict__ nkeys,
    float* __restrict__ out, u32* __restrict__ vxy, float* __restrict__ m0p)
{
  // union: stage planes (8 x LPLANE u32 = 10944 B), then pbuf (256 rows x 128 B
  // = 32768 B, chunk-swizzled), then dsb (256 x 17 f32 = 17408 B)
  __shared__ __align__(16) unsigned char smem[32768];
  u32 (*ls2)[LPLANE] = (u32 (*)[LPLANE])smem;

  const int tid  = threadIdx.x;
  const int lane = tid & 63, wv = tid >> 6;
  const int quad = lane >> 4, mm = lane & 15;
  const int bx = blockIdx.x, by = blockIdx.y, b = blockIdx.z;
  const int x0t = bx*TS, y0t = by*TS;
  const float* __restrict__ sb = st + (size_t)b*HH*WW*16;

  const int seed = seedp[0];
  const u32 k1a = nkeys[0], k1b = nkeys[1], k2a = nkeys[2], k2b = nkeys[3];

  const int lx = tid & 15, ly = tid >> 4;
  const int ygl = y0t + ly, xgl = x0t + lx;

  // own-pixel exact-f32 state: issue FIRST — L1/L2-shared with the staging
  // reads below; dead-cheap and removes the epilogue's global-load tail.
  const float* scp = sb + ((size_t)(ygl*WW + xgl))*16;
  float4 s0 = *(const float4*)(scp+0),  s1 = *(const float4*)(scp+4);
  float4 s2 = *(const float4*)(scp+8),  s3 = *(const float4*)(scp+12);

  // stage 18x18 px x 8 half2-pairs
  for (int t = tid; t < 18*18*4; t += 256){
    int pix = t >> 2, part = t & 3;
    int py = pix / 18, px = pix - py*18;
    int gy = (y0t + py - 1) & (HH-1);
    int gx = (x0t + px - 1) & (WW-1);
    const float4 v = *(const float4*)(sb + ((gy*WW + gx)*16 + part*4));
    int li = py*LROW + px;
    ls2[part*2  ][li] = h2_as_u32(__floats2half2_rn(v.x, v.y));
    ls2[part*2+1][li] = h2_as_u32(__floats2half2_rn(v.z, v.w));
  }
  __syncthreads();

  const int ctr = (ly+1)*LROW + (lx+1);

  // ---- perception in packed f16; results held in 32 u32 regs (constant-indexed) ----
  const __half2 two    = __float2half2_rn(2.0f);
  const __half2 eighth = __float2half2_rn(0.125f);
  const __half2 quart  = __float2half2_rn(0.25f);
  const __half2 neg4   = __float2half2_rn(-4.0f);
  u32 rid[8], rgx[8], rgy[8], rlp[8];
  #pragma unroll
  for (int cp = 0; cp < 8; ++cp){
    const u32* pl = ls2[cp];
    __half2 t00 = u32_as_h2(pl[ctr-LROW-1]), t01 = u32_as_h2(pl[ctr-LROW]), t02 = u32_as_h2(pl[ctr-LROW+1]);
    __half2 t10 = u32_as_h2(pl[ctr-1]),      t11 = u32_as_h2(pl[ctr]),      t12 = u32_as_h2(pl[ctr+1]);
    __half2 t20 = u32_as_h2(pl[ctr+LROW-1]), t21 = u32_as_h2(pl[ctr+LROW]), t22 = u32_as_h2(pl[ctr+LROW+1]);
    __half2 sR = __hfma2(two, t12, __hadd2(t02, t22));
    __half2 sL = __hfma2(two, t10, __hadd2(t00, t20));
    __half2 sB = __hfma2(two, t21, __hadd2(t20, t22));
    __half2 sT = __hfma2(two, t01, __hadd2(t00, t02));
    __half2 sC = __hadd2(__hadd2(t10, t12), __hadd2(t01, t21));
    rid[cp] = h2_as_u32(t11);
    rgx[cp] = h2_as_u32(__hmul2(__hsub2(sR, sL), eighth));
    rgy[cp] = h2_as_u32(__hmul2(__hsub2(sB, sT), eighth));
    rlp[cp] = h2_as_u32(__hmul2(__hfma2(neg4, t11, sC), quart));
  }

  // layer-1 B fragments + biases: issue between stencil and pack so their
  // L2 latency hides under the pack writes (stencil temps are dead here).
  f16x8 BfA[8];
  #pragma unroll
  for (int f = 0; f < 8; ++f)
    BfA[f] = *(const f16x8*)(wfrag + (f*64 + lane)*8);
  float bias1[4], bias2[2];
  #pragma unroll
  for (int nc = 0; nc < 4; ++nc) bias1[nc] = b1[nc*16 + mm];
  #pragma unroll
  for (int nc = 0; nc < 2; ++nc) bias2[nc] = b2[nc*16 + mm];
  float biasH = bcat[mm];

  __syncthreads();   // all stencil reads done; smem becomes pbuf

  // ---- pack to pbuf as 8x ds_write_b128: chunk c of row t lands at c^SW(t).
  // (identical layout to the per-dword formula: dword j -> j^(SW<<2))
  {
    u32x4* pb128 = (u32x4*)smem;
    const int rb = tid*8, sw = SW(tid);
    u32x4 v;
    v[0]=rid[0]; v[1]=rid[1]; v[2]=rid[2]; v[3]=rid[3]; pb128[rb + (0^sw)] = v;
    v[0]=rid[4]; v[1]=rid[5]; v[2]=rid[6]; v[3]=rid[7]; pb128[rb + (1^sw)] = v;
    v[0]=rgx[0]; v[1]=rgx[1]; v[2]=rgx[2]; v[3]=rgx[3]; pb128[rb + (2^sw)] = v;
    v[0]=rgx[4]; v[1]=rgx[5]; v[2]=rgx[6]; v[3]=rgx[7]; pb128[rb + (3^sw)] = v;
    v[0]=rgy[0]; v[1]=rgy[1]; v[2]=rgy[2]; v[3]=rgy[3]; pb128[rb + (4^sw)] = v;
    v[0]=rgy[4]; v[1]=rgy[5]; v[2]=rgy[6]; v[3]=rgy[7]; pb128[rb + (5^sw)] = v;
    v[0]=rlp[0]; v[1]=rlp[1]; v[2]=rlp[2]; v[3]=rlp[3]; pb128[rb + (6^sw)] = v;
    v[0]=rlp[4]; v[1]=rlp[5]; v[2]=rlp[6]; v[3]=rlp[7]; pb128[rb + (7^sw)] = v;
  }
  // from here on, all LDS traffic is intra-wave (wave wv owns pixels 64wv..64wv+63)

  const int rowbase = wv*4;
  const _Float16* pb16 = (const _Float16*)smem;
  unsigned short* pbuf = (unsigned short*)smem;

  // fragment read: 16B chunk c of row px, swizzled -> single ds_read_b128
  auto loadfrag = [&](int px, int chunk) -> f16x8 {
    return *(const f16x8*)(pb16 + px*64 + ((chunk ^ SW(px)) * 8));
  };

  // ---- layer 1 (per-gi fused compute+store: reads of gi's rows precede writes) ----
  #pragma unroll
  for (int gi = 0; gi < 4; ++gi){
    int px = (rowbase+gi)*16 + mm;
    f16x8 a0 = loadfrag(px, quad);
    f16x8 a1 = loadfrag(px, 4 + quad);
    f32x4 C[4];
    #pragma unroll
    for (int nc = 0; nc < 4; ++nc){
      f32x4 c; c[0]=bias1[nc]; c[1]=bias1[nc]; c[2]=bias1[nc]; c[3]=bias1[nc];
      c = __builtin_amdgcn_mfma_f32_16x16x32_f16(a0, BfA[nc],   c, 0,0,0);
      c = __builtin_amdgcn_mfma_f32_16x16x32_f16(a1, BfA[4+nc], c, 0,0,0);
      C[nc] = c;
    }
    #pragma unroll
    for (int nc = 0; nc < 4; ++nc)
      #pragma unroll
      for (int r = 0; r < 4; ++r){
        int row = (rowbase+gi)*16 + quad*4 + r;
        pbuf[row*64 + ((nc*16 + mm) ^ (SW(row) << 3))] =
            __half_as_ushort(__float2half(fmaxf(C[nc][r], 0.0f)));
      }
  }

  // layer-2/heads B fragments: latency hides under layer-2 MFMA
  f16x8 BfB[5];
  #pragma unroll
  for (int f = 0; f < 5; ++f)
    BfB[f] = *(const f16x8*)(wfrag + ((8+f)*64 + lane)*8);

  // ---- layer 2 ----
  #pragma unroll
  for (int gi = 0; gi < 4; ++gi){
    int px = (rowbase+gi)*16 + mm;
    f16x8 a0 = loadfrag(px, quad);
    f16x8 a1 = loadfrag(px, 4 + quad);
    f32x4 C[2];
    #pragma unroll
    for (int nc = 0; nc < 2; ++nc){
      f32x4 c; c[0]=bias2[nc]; c[1]=bias2[nc]; c[2]=bias2[nc]; c[3]=bias2[nc];
      c = __builtin_amdgcn_mfma_f32_16x16x32_f16(a0, BfB[nc],   c, 0,0,0);
      c = __builtin_amdgcn_mfma_f32_16x16x32_f16(a1, BfB[2+nc], c, 0,0,0);
      C[nc] = c;
    }
    #pragma unroll
    for (int nc = 0; nc < 2; ++nc)
      #pragma unroll
      for (int r = 0; r < 4; ++r){
        int row = (rowbase+gi)*16 + quad*4 + r;
        pbuf[row*64 + ((nc*16 + mm) ^ (SW(row) << 3))] =
            __half_as_ushort(__float2half(fmaxf(C[nc][r], 0.0f)));
      }
  }

  // ---- heads (K=32, a0 only) ----
  f32x4 C3[4];
  #pragma unroll
  for (int gi = 0; gi < 4; ++gi){
    int px = (rowbase+gi)*16 + mm;
    f16x8 a0 = loadfrag(px, quad);
    f32x4 c; c[0]=biasH; c[1]=biasH; c[2]=biasH; c[3]=biasH;
    C3[gi] = __builtin_amdgcn_mfma_f32_16x16x32_f16(a0, BfB[4], c, 0,0,0);
  }

  // ---- all three threefry draws back-to-back: independent ~84-instr serial
  // chains -> 3-way ILP instead of three separated stalls.
  const u32 pix = ((u32)b*HH + ygl)*WW + xgl;
  u32 mbits = pbits(0u, (u32)seed, pix);
  u32 nxb   = pbits(k1a, k1b, pix);
  u32 nyb   = pbits(k2a, k2b, pix);

  __syncthreads();   // dsb rows overlap other waves' pbuf rows
  {
    float* dsb = (float*)smem;   // 256 x 17 f32
    #pragma unroll
    for (int gi = 0; gi < 4; ++gi)
      #pragma unroll
      for (int r = 0; r < 4; ++r)
        dsb[((rowbase+gi)*16 + quad*4 + r)*17 + mm] = C3[gi][r];
  }

  // ---- epilogue: exact f32 ----
  const float* dsb = (const float*)smem;
  float m = ((int)mbits >= 0) ? 1.0f : 0.0f;

  float sc[16] = {s0.x,s0.y,s0.z,s0.w, s1.x,s1.y,s1.z,s1.w,
                  s2.x,s2.y,s2.z,s2.w, s3.x,s3.y,s3.z,s3.w};
  float ds[16], ns[16];
  #pragma unroll
  for (int ch = 0; ch < 16; ++ch) ds[ch] = dsb[tid*17 + ch];
  ds[3] = 0.0f; ds[6] = 0.0f; ds[7] = 0.0f;   // zero heads (cols were zero anyway)
  #pragma unroll
  for (int ch = 0; ch < 16; ++ch) ns[ch] = sc[ch] + ds[ch]*m;

  ns[4] = 0.95f * fminf(fmaxf(ns[4], -1.0f), 1.0f);
  ns[5] = 0.95f * fminf(fmaxf(ns[5], -1.0f), 1.0f);
  ns[0] = fminf(fmaxf(ns[0], 0.0f), 1.0f);
  ns[1] = fminf(fmaxf(ns[1], 0.0f), 1.0f);
  ns[2] = fminf(fmaxf(ns[2], 0.0f), 1.0f);
  ns[3] = sc[3];

  float* __restrict__ op = out + (size_t)pix*16;
  *(float4*)(op+ 0) = make_float4(ns[0],ns[1],ns[2],ns[3]);
  *(float4*)(op+ 4) = make_float4(ns[4],ns[5],ns[6],ns[7]);
  *(float4*)(op+ 8) = make_float4(ns[8],ns[9],ns[10],ns[11]);
  *(float4*)(op+12) = make_float4(ns[12],ns[13],ns[14],ns[15]);

  float vx = ns[4] + 0.2f*normal_from_bits(nxb);
  float vy = ns[5] + 0.2f*normal_from_bits(nyb);
  vxy[pix] = h2_as_u32(__floats2half2_rn(vx, vy));
  m0p[pix] = sc[3];
}

// ---------------- fused advect x2 + diffuse (halo-3 tile) ----------------
// |v| <= 0.95 + 0.2*5.6sigma ~ 2.07 -> per-step displacement <= 0.52 px < 1.
#define AT 32
__global__ __launch_bounds__(256) void advect_fused(
    const float* __restrict__ m0, const u32* __restrict__ vxy,
    float* __restrict__ out)
{
  __shared__ float sm0[38][39];
  __shared__ u32   sv [36][37];
  __shared__ float sm1[36][37];
  __shared__ float sm2[34][35];
  const int tid = threadIdx.x;
  const int X0 = blockIdx.x*AT, Y0 = blockIdx.y*AT, b = blockIdx.z;
  const size_t base = ((size_t)b) << 18;

  for (int t = tid; t < 38*38; t += 256){
    int ly = t/38, lx = t - ly*38;
    int gy = (Y0-3+ly)&511, gx = (X0-3+lx)&511;
    sm0[ly][lx] = m0[base + (gy<<9) + gx];
  }
  for (int t = tid; t < 36*36; t += 256){
    int ly = t/36, lx = t - ly*36;
    int gy = (Y0-2+ly)&511, gx = (X0-2+lx)&511;
    sv[ly][lx] = vxy[base + (gy<<9) + gx];
  }
  __syncthreads();

  // step 1: m1 on 36x36 (globals Y0-2..Y0+33)
  for (int t = tid; t < 36*36; t += 256){
    int ly = t/36, lx = t - ly*36;
    int gy = (Y0-2+ly)&511, gx = (X0-2+lx)&511;
    __half2 hv = u32_as_h2(sv[ly][lx]);
    float vx = __low2float(hv), vyv = __high2float(hv);
    float sy = (float)gy - vyv*0.25f;
    float sx = (float)gx - vx *0.25f;
    float y0f = floorf(sy), x0f = floorf(sx);
    float fy = sy - y0f, fx = sx - x0f;
    int l0y = (((int)y0f) - Y0 + 3) & 511;
    int l0x = (((int)x0f) - X0 + 3) & 511;
    float m00 = sm0[l0y][l0x],   m01 = sm0[l0y][l0x+1];
    float m10 = sm0[l0y+1][l0x], m11 = sm0[l0y+1][l0x+1];
    sm1[ly][lx] = (1.0f-fy)*((1.0f-fx)*m00 + fx*m01) + fy*((1.0f-fx)*m10 + fx*m11);
  }
  __syncthreads();

  // step 2: m2 on 34x34 (globals Y0-1..Y0+32); v local = +1
  for (int t = tid; t < 34*34; t += 256){
    int ly = t/34, lx = t - ly*34;
    int gy = (Y0-1+ly)&511, gx = (X0-1+lx)&511;
    __half2 hv = u32_as_h2(sv[ly+1][lx+1]);
    float vx = __low2float(hv), vyv = __high2float(hv);
    float sy = (float)gy - vyv*0.25f;
    float sx = (float)gx - vx *0.25f;
    float y0f = floorf(sy), x0f = floorf(sx);
    float fy = sy - y0f, fx = sx - x0f;
    int l0y = (((int)y0f) - Y0 + 2) & 511;
    int l0x = (((int)x0f) - X0 + 2) & 511;
    float m00 = sm1[l0y][l0x],   m01 = sm1[l0y][l0x+1];
    float m10 = sm1[l0y+1][l0x], m11 = sm1[l0y+1][l0x+1];
    sm2[ly][lx] = (1.0f-fy)*((1.0f-fx)*m00 + fx*m01) + fy*((1.0f-fx)*m10 + fx*m11);
  }
  __syncthreads();

  // diffuse 32x32 -> out ch3
  for (int t = tid; t < 32*32; t += 256){
    int ly = t >> 5, lx = t & 31;
    int gy = Y0 + ly, gx = X0 + lx;
    float c = sm2[ly+1][lx+1];
    float r = sm2[ly+1][lx+2], l = sm2[ly+1][lx];
    float d = sm2[ly+2][lx+1], u = sm2[ly][lx+1];
    out[(base + (gy<<9) + gx)*16 + 3] = c + 0.05f*((r+l+d+u)*0.25f - c);
  }
}

// ---------------- launch ----------------
extern "C" void kernel_launch(void* const* d_in, const int* in_sizes, int n_in,
                              void* d_out, int out_size, void* d_ws, size_t ws_size,
                              hipStream_t stream)
{
  const float* st   = (const float*)d_in[0];
  const int*   seed = (const int*)  d_in[1];
  const float* w1   = (const float*)d_in[2];
  const float* b1   = (const float*)d_in[3];
  const float* w2   = (const float*)d_in[4];
  const float* b2   = (const float*)d_in[5];
  const float* wrgb = (const float*)d_in[6];
  const float* brgb = (const float*)d_in[7];
  const float* wvel = (const float*)d_in[8];
  const float* bvel = (const float*)d_in[9];
  const float* whid = (const float*)d_in[10];
  const float* bhid = (const float*)d_in[11];
  float* out = (float*)d_out;

  const int npix = NB*HH*WW;                 // 2^21
  float* m0p = (float*)d_ws;                 // 8 MB
  u32*   vxy = (u32*)(m0p + npix);           // 8 MB
  unsigned short* wfrag = (unsigned short*)(vxy + npix);  // 13312 B
  float* bcat = (float*)(wfrag + 13*64*8);   // 64 B
  u32* nkeys = (u32*)(bcat + 16);            // 16 B

  prep_w<<<1, 256, 0, stream>>>(w1, w2, wrgb, wvel, whid, brgb, bvel, bhid, seed,
                                wfrag, bcat, nkeys);

  dim3 gridA(WW/TS, HH/TS, NB);
  nca_main<<<gridA, 256, 0, stream>>>(st, seed, b1, b2, wfrag, bcat, nkeys, out, vxy, m0p);

  dim3 gridB(WW/AT, HH/AT, NB);
  advect_fused<<<gridB, 256, 0, stream>>>(m0p, vxy, out);
}